// Round 5
// baseline (576.560 us; speedup 1.0000x reference)
//
#include <hip/hip_runtime.h>
#include <hip/hip_bf16.h>

#define Bb 1024
#define NN 50
#define KK 8
#define DD 128
#define CC 51
#define LDK 136   // bf16 elems per LDS row (272 B, 16B-aligned)

typedef __attribute__((ext_vector_type(8))) short short8;
typedef __attribute__((ext_vector_type(4))) float f32x4;

__device__ __forceinline__ unsigned short f2bf(float f) {
  union { float f; unsigned int u; } un; un.f = f;
  unsigned int r = un.u + 0x7fffu + ((un.u >> 16) & 1u);
  return (unsigned short)(r >> 16);
}
__device__ __forceinline__ float bf2f(unsigned short h) {
  union { unsigned int u; float f; } un; un.u = ((unsigned int)h) << 16;
  return un.f;
}
__device__ __forceinline__ unsigned int pk2(float a, float b) {
  return (unsigned int)f2bf(a) | ((unsigned int)f2bf(b) << 16);
}

// ---------------- workspace layout (bytes) ----------------
static constexpr size_t SZ_BCD  = (size_t)Bb * CC * DD;        // 6684672
static constexpr size_t OFF_BN  = SZ_BCD * 2;                  // after H1bf
static constexpr size_t OFF_H2  = OFF_BN + 1024;
static constexpr size_t OFF_M   = OFF_H2 + (size_t)Bb * DD * 4;

// ---------------- K0: M = attW^T attW, u = attW^T b, bbsq = b.b ----------------
__global__ __launch_bounds__(128) void k0_prep(
    const float* __restrict__ attW, const float* __restrict__ attb,
    float* __restrict__ M) {
  int d = blockIdx.x, e = threadIdx.x;
  float m = 0.f, ub = 0.f;
#pragma unroll 4
  for (int k = 0; k < DD; ++k) {
    float wd = attW[(size_t)k * DD + d];   // broadcast
    m  += attW[(size_t)k * DD + e] * wd;   // coalesced
    ub += wd * attb[k];
  }
  M[(size_t)e * DD + d] = m;
  if (e == 0) M[DD * DD + d] = ub;
  if (d == 0 && e == 0) {
    float bb = 0.f;
    for (int k = 0; k < DD; ++k) bb += attb[k] * attb[k];
    M[DD * DD + DD] = bb;
  }
}

// ---------------- MEGA: gather + attention + GEMM(MFMA) + adj@X + BN1 stats ----------------
__global__ __launch_bounds__(256) void mega(
    const int* __restrict__ hrt, const int* __restrict__ neb,
    const int* __restrict__ nebr, const float* __restrict__ entW,
    const float* __restrict__ relW, const float* __restrict__ adj,
    const float* __restrict__ gcnW, const float* __restrict__ gcnb,
    const float* __restrict__ Mext, unsigned short* __restrict__ H1bf,
    float* __restrict__ bn1, float* __restrict__ out) {
  __shared__ float ss[DD], sw[DD], sl[64];
  __shared__ float cval;
  __shared__ float shA[52 * 132];   // sub (50*132) ; later Xl (52*132)
  __shared__ float shAb[3536];      // Ab: bf16 52*LDK = 7072 shorts
  __shared__ float shB[8704];       // Bb: bf16 128*LDK shorts ; later Al adj 51*52 f32

  int b = blockIdx.x, t = threadIdx.x;
  float* sub = shA;
  unsigned short* Ab = (unsigned short*)shAb;
  unsigned short* Bbuf = (unsigned short*)shB;

  // phase 1a: hrt gathers + sum_hrt (threads 0..31)
  if (t < 32) {
    int hi = hrt[b * 3 + 0], ri = hrt[b * 3 + 1], ti = hrt[b * 3 + 2];
    float4 hv = ((const float4*)(entW + (size_t)hi * DD))[t];
    float4 tv = ((const float4*)(entW + (size_t)ti * DD))[t];
    float4 rv = ((const float4*)(relW + (size_t)ri * DD))[t];
    ((float4*)(out + (size_t)b * DD))[t] = hv;
    ((float4*)(out + (size_t)Bb * DD + (size_t)b * DD))[t] = tv;
    ((float4*)(out + (size_t)2 * Bb * DD + (size_t)b * DD))[t] = rv;
    const float inv3 = 1.f / 3.f;
    float4 s;
    s.x = (hv.x + tv.x + rv.x) * inv3;
    s.y = (hv.y + tv.y + rv.y) * inv3;
    s.z = (hv.z + tv.z + rv.z) * inv3;
    s.w = (hv.w + tv.w + rv.w) * inv3;
    ((float4*)ss)[t] = s;
  }
  // phase 1b: stage gcnW -> bf16 Bbuf (L2-hot, overlaps with gathers)
  for (int idx = t; idx < 4096; idx += 256) {
    int d = idx >> 5, g = idx & 31;
    float4 v = ((const float4*)(gcnW + (size_t)d * DD))[g];
    ushort4 p;
    p.x = f2bf(v.x); p.y = f2bf(v.y); p.z = f2bf(v.z); p.w = f2bf(v.w);
    *((ushort4*)(Bbuf + d * LDK + g * 4)) = p;
  }
  // phase 1c: neighbor gathers -> sub (LDS only)
  for (int idx = t; idx < NN * 32; idx += 256) {
    int r = idx >> 5, c4 = idx & 31;
    int e = neb[b * NN + r];
    float4 ev = ((const float4*)(entW + (size_t)e * DD))[c4];
    const int* rb = nebr + ((size_t)(b * NN + r)) * KK;
    float4 rs = make_float4(0.f, 0.f, 0.f, 0.f);
#pragma unroll
    for (int k = 0; k < KK; ++k) {
      float4 rv = ((const float4*)(relW + (size_t)rb[k] * DD))[c4];
      rs.x += rv.x; rs.y += rv.y; rs.z += rv.z; rs.w += rv.w;
    }
    float4 sg;
    sg.x = 0.5f * (ev.x + rs.x * 0.125f);
    sg.y = 0.5f * (ev.y + rs.y * 0.125f);
    sg.z = 0.5f * (ev.z + rs.z * 0.125f);
    sg.w = 0.5f * (ev.w + rs.w * 0.125f);
    ((float4*)(sub + r * 132))[c4] = sg;
  }
  __syncthreads();
  // phase 2: w = M.s + u (coalesced column reads of symmetric M); c = s.u + bbsq
  if (t < DD) {
    float w = 0.f;
#pragma unroll 4
    for (int e = 0; e < DD; ++e) w += Mext[(size_t)e * DD + t] * ss[e];
    sw[t] = w + Mext[DD * DD + t];
  }
  if (t >= 128 && t < 192) {
    int l = t - 128;
    const float* u = Mext + DD * DD;
    float v = ss[l] * u[l] + ss[l + 64] * u[l + 64];
#pragma unroll
    for (int m = 1; m < 64; m <<= 1) v += __shfl_xor(v, m);
    if (l == 0) cval = v + u[DD];
  }
  __syncthreads();
  // phase 3: logits (4 threads per row)
  if (t < NN * 4) {
    int n = t >> 2, q = t & 3;
    const float* sg = sub + n * 132 + q * 32;
    const float* wq = sw + q * 32;
    float L = 0.f;
#pragma unroll 8
    for (int e = 0; e < 32; ++e) L += sg[e] * wq[e];
    L += __shfl_xor(L, 1);
    L += __shfl_xor(L, 2);
    if (q == 0) {
      L += cval;
      sl[n] = (L > 0.f) ? L : 0.01f * L;
    }
  }
  __syncthreads();
  // phase 4: softmax over 50 (wave 0)
  if (t < 64) {
    float v = (t < NN) ? sl[t] : -1e30f;
    float mx = v;
#pragma unroll
    for (int m = 1; m < 64; m <<= 1) mx = fmaxf(mx, __shfl_xor(mx, m));
    float e = (t < NN) ? __expf(v - mx) : 0.f;
    float sm = e;
#pragma unroll
    for (int m = 1; m < 64; m <<= 1) sm += __shfl_xor(sm, m);
    if (t < NN) sl[t] = e / sm;
  }
  __syncthreads();
  // phase 5: build A (bf16 Y): row0 = ss, rows 1..50 = sl[n]*sub[n], row 51 = 0
  for (int idx = t; idx < 52 * 16; idx += 256) {
    int r = idx >> 4, c8 = (idx & 15) * 8;
    uint4 p = make_uint4(0u, 0u, 0u, 0u);
    if (r == 0) {
      const float* s8 = ss + c8;
      p.x = pk2(s8[0], s8[1]); p.y = pk2(s8[2], s8[3]);
      p.z = pk2(s8[4], s8[5]); p.w = pk2(s8[6], s8[7]);
    } else if (r <= NN) {
      float a = sl[r - 1];
      const float* s8 = sub + (r - 1) * 132 + c8;
      p.x = pk2(a * s8[0], a * s8[1]); p.y = pk2(a * s8[2], a * s8[3]);
      p.z = pk2(a * s8[4], a * s8[5]); p.w = pk2(a * s8[6], a * s8[7]);
    }
    *((uint4*)(Ab + r * LDK + c8)) = p;
  }
  __syncthreads();
  // phase 6: MFMA  X(64x128) = A(64x128) @ B^T ; wave wv -> rows wv*16..+15
  int wv = t >> 6, lane = t & 63;
  int m16 = lane & 15;
  int q8 = (lane >> 4) * 8;
  f32x4 acc[8] = {};
  const unsigned short* Abase = Ab + (wv * 16 + m16) * LDK + q8;
  const unsigned short* Bbase = Bbuf + m16 * LDK + q8;
#pragma unroll
  for (int ks = 0; ks < 4; ++ks) {
    short8 a0 = *(const short8*)(Abase + ks * 32);
#pragma unroll
    for (int nt = 0; nt < 8; ++nt) {
      short8 bb = *(const short8*)(Bbase + nt * 16 * LDK + ks * 32);
      acc[nt] = __builtin_amdgcn_mfma_f32_16x16x32_bf16(a0, bb, acc[nt], 0, 0, 0);
    }
  }
  __syncthreads();   // A/B LDS dead; safe to overlay
  // phase 7a: X -> LDS (fp32, rows < 51), + bias
  float* Xl = shA;
  int qd = (lane >> 4) * 4;
#pragma unroll
  for (int nt = 0; nt < 8; ++nt) {
    float bias = gcnb[nt * 16 + m16];
#pragma unroll
    for (int r = 0; r < 4; ++r) {
      int row = wv * 16 + qd + r;
      if (row < CC) Xl[row * 132 + nt * 16 + m16] = acc[nt][r] + bias;
    }
  }
  // phase 7b: stage adj_b (51x51, stride 52)
  float* Al = shB;
  for (int idx = t; idx < 51 * 64; idx += 256) {
    int i = idx >> 6, j = idx & 63;
    if (j < CC) Al[i * 52 + j] = adj[(size_t)b * (CC * CC) + i * CC + j];
  }
  __syncthreads();
  // phase 8: H1 = relu(adj @ X), BN1 partial stats. 256 thr: tc=0..31 cols4, tr=0..7
  {
    int tc = t & 31, tr = t >> 5;
    float4 acc4[7];
#pragma unroll
    for (int k = 0; k < 7; ++k) acc4[k] = make_float4(0.f, 0.f, 0.f, 0.f);
    for (int jj = 0; jj < CC; ++jj) {
      float4 xv = ((const float4*)(Xl + jj * 132))[tc];
#pragma unroll
      for (int k = 0; k < 7; ++k) {
        int i = tr + 8 * k;
        float a = (i < CC) ? Al[i * 52 + jj] : 0.f;
        acc4[k].x += a * xv.x; acc4[k].y += a * xv.y;
        acc4[k].z += a * xv.z; acc4[k].w += a * xv.w;
      }
    }
#pragma unroll
    for (int k = 0; k < 7; ++k) {
      int i = tr + 8 * k;
      if (i < CC) {
        float4 h;
        h.x = fmaxf(acc4[k].x, 0.f); h.y = fmaxf(acc4[k].y, 0.f);
        h.z = fmaxf(acc4[k].z, 0.f); h.w = fmaxf(acc4[k].w, 0.f);
        ushort4 p;
        p.x = f2bf(h.x); p.y = f2bf(h.y); p.z = f2bf(h.z); p.w = f2bf(h.w);
        ((ushort4*)(H1bf + ((size_t)b * CC + i) * DD))[tc] = p;
        float s = h.x + h.y + h.z + h.w;
        float qq = h.x * h.x + h.y * h.y + h.z * h.z + h.w * h.w;
#pragma unroll
        for (int m = 1; m < 32; m <<= 1) {
          s += __shfl_xor(s, m);
          qq += __shfl_xor(qq, m);
        }
        if (tc == 0) {
          atomicAdd(&bn1[i], s);
          atomicAdd(&bn1[64 + i], qq);
        }
      }
    }
  }
}

// ---------------- K6: h2 = relu(adj0 @ BN1(H1)), BN2 partial stats ----------------
__global__ __launch_bounds__(128) void k6_row0(
    const unsigned short* __restrict__ H1bf, const float* __restrict__ adj,
    const float* __restrict__ bn1, const float* __restrict__ gamma,
    const float* __restrict__ beta, float* __restrict__ h2,
    float* __restrict__ bn2) {
  __shared__ float cj[52];
  __shared__ float td[64];
  __shared__ float reds[128], redq[128];
  int b = blockIdx.x, t = threadIdx.x;   // t == d
  const float invBD = 1.f / ((float)Bb * (float)DD);
  if (t < 64) td[t] = 0.f;
  if (t < CC) {
    float s = bn1[t], q = bn1[64 + t];
    float m = s * invBD;
    float v = fmaxf(q * invBD - m * m, 0.f);
    float inv = rsqrtf(v + 1e-5f);
    float al = gamma[t] * inv;
    float de = beta[t] - m * al;
    float a0 = adj[(size_t)b * (CC * CC) + t];
    cj[t] = a0 * al;
    td[t] = a0 * de;
  }
  __syncthreads();
  float tcst = 0.f;
  for (int j = 0; j < CC; ++j) tcst += td[j];
  float acc = tcst;
  const unsigned short* hb = H1bf + (size_t)b * CC * DD + t;
#pragma unroll 4
  for (int j = 0; j < CC; ++j) acc += cj[j] * bf2f(hb[(size_t)j * DD]);
  acc = fmaxf(acc, 0.f);
  h2[(size_t)b * DD + t] = acc;
  reds[t] = acc;
  redq[t] = acc * acc;
  __syncthreads();
  for (int s = 64; s > 0; s >>= 1) {
    if (t < s) { reds[t] += reds[t + s]; redq[t] += redq[t + s]; }
    __syncthreads();
  }
  if (t == 0) {
    atomicAdd(&bn2[0], reds[0]);
    atomicAdd(&bn2[1], redq[0]);
  }
}

// ---------------- K8: tri_em = BN2(h2) ----------------
__global__ __launch_bounds__(256) void k8_final(
    const float* __restrict__ h2, const float* __restrict__ bn2,
    const float* __restrict__ gamma, const float* __restrict__ beta,
    float* __restrict__ out) {
  int i = blockIdx.x * 256 + threadIdx.x;
  const float invBD = 1.f / ((float)Bb * (float)DD);
  float m = bn2[0] * invBD;
  float v = fmaxf(bn2[1] * invBD - m * m, 0.f);
  float inv = rsqrtf(v + 1e-5f);
  out[(size_t)3 * Bb * DD + i] = (h2[i] - m) * inv * gamma[0] + beta[0];
}

extern "C" void kernel_launch(void* const* d_in, const int* in_sizes, int n_in,
                              void* d_out, int out_size, void* d_ws, size_t ws_size,
                              hipStream_t stream) {
  (void)in_sizes; (void)n_in; (void)out_size; (void)ws_size;
  const int*   hrt   = (const int*)d_in[0];
  const int*   neb   = (const int*)d_in[1];
  const int*   nebr  = (const int*)d_in[2];
  const float* adj   = (const float*)d_in[3];
  const float* entW  = (const float*)d_in[4];
  const float* relW  = (const float*)d_in[5];
  const float* attW  = (const float*)d_in[6];
  const float* attb  = (const float*)d_in[7];
  const float* gcnW  = (const float*)d_in[8];
  const float* gcnb  = (const float*)d_in[9];
  const float* gamma = (const float*)d_in[10];
  const float* beta  = (const float*)d_in[11];
  float* out = (float*)d_out;
  char*  ws  = (char*)d_ws;

  unsigned short* H1bf = (unsigned short*)ws;
  float*          bn1  = (float*)(ws + OFF_BN);
  float*          bn2  = bn1 + 128;
  float*          h2   = (float*)(ws + OFF_H2);
  float*          Mext = (float*)(ws + OFF_M);

  hipMemsetAsync((void*)bn1, 0, 1024, stream);   // zero BN accumulators

  k0_prep<<<DD, DD, 0, stream>>>(attW, attb, Mext);
  mega<<<Bb, 256, 0, stream>>>(hrt, neb, nebr, entW, relW, adj, gcnW, gcnb,
                               Mext, H1bf, bn1, out);
  k6_row0<<<Bb, 128, 0, stream>>>(H1bf, adj, bn1, gamma, beta, h2, bn2);
  k8_final<<<(Bb * DD) / 256, 256, 0, stream>>>(h2, bn2, gamma, beta, out);
}